// Round 8
// baseline (2022.440 us; speedup 1.0000x reference)
//
#include <hip/hip_runtime.h>
#include <stdint.h>

// FFJORD block: B=2048, D=512, H=1024, 9 RK38 steps x 4 stages, 2 Hutchinson probes.
// f32 in/out. bf16 MFMA GEMMs, f32 accumulate, fp32 RK state.
// PRNG: JAX threefry partitionable (verified R7).
// R22: RK state in LDS. R21 post-mortem: state-in-REGISTERS spilled (VGPR
// pegged 256; FETCH +370MB of scratch traffic, time 1414->1670). The idea
// (state never crosses blocks -> keep local) was right, placement wrong.
// Fix: z/ACC/T tiles in LDS: ring 112KB + 3x16KB state = exactly 160KB
// (full gfx950 LDS, still 1 block/CU). Each thread touches only its own 16
// state elems -> no sync; col-rotation swizzle (col+q*16)&63 -> 2-way bank
// aliasing (free, m136). Else identical to R21/R19: fence-free slab
// barriers, sc0 staging, f1 4-ring vmcnt(14), f3 K64 4-ring vmcnt(8),
// balanced egen (1 unit/thread/stage in f3 phase).

#define B_N 2048
#define D_N 512
#define H_N 1024
#define BD (B_N * D_N)

typedef unsigned short u16;
typedef __attribute__((ext_vector_type(8))) short s16x8;   // 8 x bf16
typedef __attribute__((ext_vector_type(4))) float f32x4;   // MFMA accumulator

typedef __attribute__((address_space(1))) const uint32_t ga_u32;
typedef __attribute__((address_space(3))) uint32_t ls_u32;

#if __has_builtin(__builtin_amdgcn_alignbit)
#define ROTL32(x, r) __builtin_amdgcn_alignbit((x), (x), 32 - (r))
#else
#define ROTL32(x, r) (((x) << (r)) | ((x) >> (32 - (r))))
#endif

__device__ __forceinline__ u16 f2bf(float f) {
  union { float f; uint32_t u; } c; c.f = f;
  uint32_t r = c.u + 0x7FFFu + ((c.u >> 16) & 1u);  // RTNE
  return (u16)(r >> 16);
}
__device__ __forceinline__ float fast_tanh(float v) {
  float e = __expf(2.0f * fabsf(v));
  float t = 1.0f - 2.0f / (e + 1.0f);
  return copysignf(t, v);
}

struct U2 { uint32_t x, y; };

// Threefry-2x32, 20 rounds — KAT-verified.
__device__ __forceinline__ U2 tf2x32(uint32_t k0, uint32_t k1, uint32_t x0, uint32_t x1) {
  uint32_t k2 = k0 ^ k1 ^ 0x1BD11BDAu;
#define RND(r) { x0 += x1; x1 = ROTL32(x1, r); x1 ^= x0; }
  x0 += k0; x1 += k1;
  RND(13) RND(15) RND(26) RND(6)
  x0 += k1; x1 += k2 + 1u;
  RND(17) RND(29) RND(16) RND(24)
  x0 += k2; x1 += k0 + 2u;
  RND(13) RND(15) RND(26) RND(6)
  x0 += k0; x1 += k1 + 3u;
  RND(17) RND(29) RND(16) RND(24)
  x0 += k1; x1 += k2 + 4u;
  RND(13) RND(15) RND(26) RND(6)
  x0 += k2; x1 += k0 + 5u;
#undef RND
  U2 r; r.x = x0; r.y = x1; return r;
}

// Partitionable key schedule (verified R7).
__global__ void k_keysched(uint32_t* __restrict__ ekeys) {
  if (threadIdx.x != 0 || blockIdx.x != 0) return;
  uint32_t kx = 0u, ky = 1234u;
  for (int s = 0; s < 9; ++s) {
    for (int st = 0; st < 4; ++st) {
      U2 kst = tf2x32(kx, ky, 0u, (uint32_t)(st + 1));
      for (int pr = 0; pr < 2; ++pr) {
        U2 fo = tf2x32(kst.x, kst.y, 0u, (uint32_t)pr);
        U2 k2 = tf2x32(fo.x, fo.y, 0u, 1u);
        ekeys[(s * 4 + st) * 4 + pr * 2 + 0] = k2.x;
        ekeys[(s * 4 + st) * 4 + pr * 2 + 1] = k2.y;
      }
    }
    U2 c = tf2x32(kx, ky, 0u, 0u);
    kx = c.x; ky = c.y;
  }
}

__global__ void k_init(const float* __restrict__ x, u16* __restrict__ zin,
                       float* __restrict__ lp, float* __restrict__ d0, float* __restrict__ d1,
                       uint32_t* __restrict__ barv) {
  int i = blockIdx.x * 256 + threadIdx.x;
  if (i < BD) zin[i] = f2bf(x[i]);
  if (i < B_N) { lp[i] = 0.f; d0[i] = 0.f; d1[i] = 0.f; }
  if (i < 1024) barv[i] = 0u;                    // 32 slab counters, 128B stride
}

__global__ void k_cvtT(const float* __restrict__ src, u16* __restrict__ dst, int R, int C) {
  int i = blockIdx.x * 256 + threadIdx.x;
  if (i >= R * C) return;
  int c = i / R, r = i - c * R;
  dst[i] = f2bf(src[(size_t)r * C + c]);
}
__global__ void k_cvt(const float* __restrict__ src, u16* __restrict__ dst, int n) {
  int i = blockIdx.x * 256 + threadIdx.x;
  if (i < n) dst[i] = f2bf(src[i]);
}

__global__ void k_sentinel(float* __restrict__ out, int n) {
  int i = blockIdx.x * 256 + threadIdx.x;
  if (i < n) out[i] = 12345.0f;
}

// 8-way slab barrier, fence-free (monotonic counter, re-zeroed each replay).
// All 8 participants share one XCD L2 (the coherence point): L1 is
// write-through so stores reach L2 at vmcnt retirement; consumers bypass
// stale L1 via sc0 loads / L2 atomics. No buffer_wbl2 / buffer_inv.
__device__ __forceinline__ void slab_bar(uint32_t* ctr, uint32_t tgt) {
  asm volatile("s_waitcnt vmcnt(0)" ::: "memory");
  __syncthreads();
  if (threadIdx.x == 0) {
    __hip_atomic_fetch_add(ctr, 1u, __ATOMIC_RELAXED, __HIP_MEMORY_SCOPE_AGENT);
    while (__hip_atomic_load(ctr, __ATOMIC_RELAXED, __HIP_MEMORY_SCOPE_AGENT) < tgt)
      __builtin_amdgcn_s_sleep(1);
  }
  __syncthreads();
}

// LDS chunk swizzle (R13-verified): chunk c of 16-row-group row r at chunk c^((r>>1)&3).
// f1: 64x128 block tile, 4 waves of 32x64, K=512, 16 K-steps, 4-ring vmcnt(14).
// f3: 64x64 block tile, 4 waves of 32x32, K=1024, 16 K64-steps, 4-ring vmcnt(8).
__global__ __launch_bounds__(256, 1)
void k_fused(const uint32_t* __restrict__ keys, u16* __restrict__ ebf,
             const float* __restrict__ x, u16* __restrict__ zin,
             const u16* __restrict__ W1T, const u16* __restrict__ W2b, const u16* __restrict__ W2T,
             const float* __restrict__ b1v, const float* __restrict__ tw1v, const float* __restrict__ b2v,
             u16* __restrict__ hbuf,
             float* __restrict__ lp, float* __restrict__ div0, float* __restrict__ div1,
             uint32_t* __restrict__ barv, float* __restrict__ outp) {
  __shared__ u16 S[4][14336];    // 112KB: f1 ring [zin|e0|e1|W1|W2]x4; f3 ring (4x8192) aliased
  __shared__ float STz[4096];    // 16KB z   (64x64, col-rotated)
  __shared__ float STa[4096];    // 16KB ACC
  __shared__ float STt[4096];    // 16KB T   — total LDS 163840 B = 160KB exactly
  const int tid = threadIdx.x, wave = tid >> 6, lane = tid & 63;
  const int xcd = blockIdx.x & 7, idx = blockIdx.x >> 3;   // 256 blocks: 32/XCD
  const int bm = xcd * 4 + (idx >> 3);       // row-slab of 64, pinned to XCD
  const int bh = idx & 7;                    // f1: col-block of 128; f3: col-block of 64
  const int row0 = bm * 64;
  const int wm = wave >> 1, wn = wave & 1, r16 = lane & 15, q = lane >> 4;
  const int srow = lane >> 2;
  const int scol = (((lane & 3) ^ ((srow >> 1) & 3))) * 8;   // swizzled source chunk
  const int cqa = (q ^ ((r16 >> 1) & 3)) * 8;                // swizzled read chunk

  uint32_t* ctr = barv + bm * 32;            // this slab's barrier counter
  uint32_t tgt = 0;

  // State tile addressing: element (i,j,rr) <-> local row lrow=wm*32+i*16+q*4+rr,
  // local col lcol=wn*32+j*16+r16; LDS slot = lrow*64 + ((lcol + q*16)&63).
  // Each thread owns its 16 slots exclusively -> no sync needed; 2-way bank alias.
#define ST_IDX(i, rr, j) (((wm * 32 + (i) * 16 + q * 4 + (rr)) << 6) + \
                          ((wn * 32 + (j) * 16 + r16 + q * 16) & 63))

  // Load initial z from x; zero ACC/T.
#pragma unroll
  for (int i = 0; i < 2; ++i)
#pragma unroll
    for (int j = 0; j < 2; ++j)
#pragma unroll
      for (int rr = 0; rr < 4; ++rr) {
        const size_t idx2 = (size_t)(row0 + wm * 32 + i * 16 + q * 4 + rr) * D_N
                          + bh * 64 + wn * 32 + j * 16 + r16;
        const int si = ST_IDX(i, rr, j);
        STz[si] = x[idx2];
        STa[si] = 0.f; STt[si] = 0.f;
      }

  // ---- egen: one (stage, unit) task per call; slab-local ----
  auto egen_unit = [&](int stg, int u) {
    const int probe = u >> 10, unit = u & 1023;
    const uint32_t p0 = (uint32_t)(bm * 32768 + unit * 32);
    uint32_t k0 = keys[stg * 4 + probe * 2], k1 = keys[stg * 4 + probe * 2 + 1];
    uint4* dst = (uint4*)(ebf + (size_t)(stg & 3) * (2 * (size_t)BD) + (size_t)probe * BD + (size_t)p0);
#pragma unroll
    for (int g = 0; g < 4; ++g) {
      uint32_t pr[4];
#pragma unroll
      for (int h = 0; h < 4; ++h) {
        uint32_t c0 = p0 + g * 8 + h * 2;
        U2 r0 = tf2x32(k0, k1, 0u, c0);
        U2 r1 = tf2x32(k0, k1, 0u, c0 + 1u);
        pr[h] = (((r0.x ^ r0.y) & 1u) ? 0x3F80u : 0xBF80u) |
                (((r1.x ^ r1.y) & 1u) ? 0x3F800000u : 0xBF800000u);
      }
      uint4 v; v.x = pr[0]; v.y = pr[1]; v.z = pr[2]; v.w = pr[3];
      dst[g] = v;
    }
  };

  // Prologue: e for stages 0..3 of this slab (2048 threads x 4 tasks).
#pragma unroll
  for (int r = 0; r < 4; ++r) egen_unit(r, bh * 256 + tid);
  tgt += 8; slab_bar(ctr, tgt);

  for (int st = 0; st < 36; ++st) {
    const int s9 = st >> 2, rsub = st & 3;
    const float t0f = (float)s9 / 9.0f;
    const float t1f = (float)(s9 + 1) / 9.0f;
    const float dtt = t1f - t0f;
    const float tstage = (rsub == 0) ? t0f : (rsub == 1) ? (t0f + dtt / 3.0f)
                       : (rsub == 2) ? (t0f + dtt * 2.0f / 3.0f) : t1f;
    const float wdt = dtt * 0.125f * ((rsub == 1 || rsub == 2) ? 3.0f : 1.0f);

    // ================= f1 phase =================
    {
      const u16* e0g = ebf + (size_t)(st & 3) * (2 * (size_t)BD);
      const u16* e1g = e0g + BD;
      const int col0 = bh * 128;

      f32x4 az[2][4], au0[2][4], au1[2][4], av0[2][4], av1[2][4];
#pragma unroll
      for (int i = 0; i < 2; ++i)
#pragma unroll
        for (int j = 0; j < 4; ++j) {
          az[i][j] = (f32x4){0,0,0,0}; au0[i][j] = (f32x4){0,0,0,0}; au1[i][j] = (f32x4){0,0,0,0};
          av0[i][j] = (f32x4){0,0,0,0}; av1[i][j] = (f32x4){0,0,0,0};
        }

      // slot s = li*4+wave: s<12 -> A {zin,e0,e1} part s&3; s>=12 -> B {W1T,W2b} part (s-12)&7
      const u16* gp[7];
#pragma unroll
      for (int li = 0; li < 7; ++li) {
        const int s = li * 4 + wave;
        const u16* base;
        int row;
        if (s < 12) {
          const int mat = s >> 2;
          base = (mat == 0) ? zin : (mat == 1) ? e0g : e1g;
          row = row0 + (s & 3) * 16 + srow;
        } else {
          const int t = s - 12;
          base = (t < 8) ? W1T : W2b;
          row = col0 + (t & 7) * 16 + srow;
        }
        gp[li] = base + (size_t)row * 512 + scol;
      }

      auto stg1 = [&](int kt, int slot) {
        u16* b = &S[slot][0];
#pragma unroll
        for (int li = 0; li < 7; ++li)
          __builtin_amdgcn_global_load_lds((ga_u32*)(gp[li] + kt),
                                           (ls_u32*)(b + (li * 4 + wave) * 512), 16, 0, 1); // sc0
      };
      auto cmp1 = [&](int slot) {
        const u16* b = &S[slot][0];
        s16x8 zf[2], e0f[2], e1f[2], w1f[4], w2f[4];
#pragma unroll
        for (int i = 0; i < 2; ++i) {
          const int ao = (wm * 32 + i * 16 + r16) * 32 + cqa;
          zf[i]  = *(const s16x8*)(b + 0    + ao);
          e0f[i] = *(const s16x8*)(b + 2048 + ao);
          e1f[i] = *(const s16x8*)(b + 4096 + ao);
        }
#pragma unroll
        for (int j = 0; j < 4; ++j) {
          const int bo = (wn * 64 + j * 16 + r16) * 32 + cqa;
          w1f[j] = *(const s16x8*)(b + 6144  + bo);
          w2f[j] = *(const s16x8*)(b + 10240 + bo);
        }
#pragma unroll
        for (int i = 0; i < 2; ++i)
#pragma unroll
          for (int j = 0; j < 4; ++j) {
            az[i][j]  = __builtin_amdgcn_mfma_f32_16x16x32_bf16(zf[i],  w1f[j], az[i][j],  0, 0, 0);
            au0[i][j] = __builtin_amdgcn_mfma_f32_16x16x32_bf16(e0f[i], w1f[j], au0[i][j], 0, 0, 0);
            au1[i][j] = __builtin_amdgcn_mfma_f32_16x16x32_bf16(e1f[i], w1f[j], au1[i][j], 0, 0, 0);
            av0[i][j] = __builtin_amdgcn_mfma_f32_16x16x32_bf16(e0f[i], w2f[j], av0[i][j], 0, 0, 0);
            av1[i][j] = __builtin_amdgcn_mfma_f32_16x16x32_bf16(e1f[i], w2f[j], av1[i][j], 0, 0, 0);
          }
      };

      // 4-slot ring, 3 ahead: 21 outstanding/wave; vmcnt(14) completes oldest 7.
      stg1(0, 0); stg1(32, 1); stg1(64, 2);
      for (int it = 0; it < 16; ++it) {
        if (it < 14)        asm volatile("s_waitcnt vmcnt(14)" ::: "memory");
        else if (it == 14)  asm volatile("s_waitcnt vmcnt(7)" ::: "memory");
        else                asm volatile("s_waitcnt vmcnt(0)" ::: "memory");
        __builtin_amdgcn_s_barrier();
        if (it + 3 < 16) stg1((it + 3) * 32, (it + 3) & 3);
        cmp1(it & 3);
      }

      float d0s[2][4], d1s[2][4];
#pragma unroll
      for (int i = 0; i < 2; ++i)
#pragma unroll
        for (int rr = 0; rr < 4; ++rr) { d0s[i][rr] = 0.f; d1s[i][rr] = 0.f; }

#pragma unroll
      for (int j = 0; j < 4; ++j) {
        const int gcol = col0 + wn * 64 + j * 16 + r16;
        const float colb = b1v[gcol] + tstage * tw1v[gcol];
#pragma unroll
        for (int i = 0; i < 2; ++i) {
          const int rbase = row0 + wm * 32 + i * 16 + q * 4;   // C/D: row=quad*4+reg
#pragma unroll
          for (int rr = 0; rr < 4; ++rr) {
            float hv = fast_tanh(az[i][j][rr] + colb);
            hbuf[(size_t)(rbase + rr) * H_N + gcol] = f2bf(hv);
            float sd = 1.f - hv * hv;
            d0s[i][rr] += sd * au0[i][j][rr] * av0[i][j][rr];
            d1s[i][rr] += sd * au1[i][j][rr] * av1[i][j][rr];
          }
        }
      }
#pragma unroll
      for (int i = 0; i < 2; ++i)
#pragma unroll
        for (int rr = 0; rr < 4; ++rr) {
          float a = d0s[i][rr], bb = d1s[i][rr];
#pragma unroll
          for (int m = 1; m < 16; m <<= 1) { a += __shfl_xor(a, m); bb += __shfl_xor(bb, m); }
          if (r16 == 0) {
            int grow = row0 + wm * 32 + i * 16 + q * 4 + rr;
            atomicAdd(&div0[grow], a);
            atomicAdd(&div1[grow], bb);
          }
        }
    }
    tgt += 8; slab_bar(ctr, tgt);

    // ================= f3 phase (+ lp/div apply, + egen for stage st+4) =================
    {
      const int col0 = bh * 64;
      u16* S3 = &S[0][0];      // 4 ring slots of 8192 u16: [A k0 2048|A k1 2048|B k0 2048|B k1 2048]

      f32x4 a3[2][2];
      a3[0][0] = (f32x4){0,0,0,0}; a3[0][1] = (f32x4){0,0,0,0};
      a3[1][0] = (f32x4){0,0,0,0}; a3[1][1] = (f32x4){0,0,0,0};

      const u16* gp3a = hbuf + (size_t)(row0 + wave * 16 + srow) * 1024 + scol;
      const u16* gp3b = W2T  + (size_t)(col0 + wave * 16 + srow) * 1024 + scol;

      // K-step 64: 4 loads/wave/step (A k0, A k1, B k0, B k1).
      auto stg3 = [&](int kt, int slot) {
        u16* b = S3 + slot * 8192;
        __builtin_amdgcn_global_load_lds((ga_u32*)(gp3a + kt),
                                         (ls_u32*)(b + wave * 512), 16, 0, 1);            // sc0
        __builtin_amdgcn_global_load_lds((ga_u32*)(gp3a + kt + 32),
                                         (ls_u32*)(b + 2048 + wave * 512), 16, 0, 1);     // sc0
        __builtin_amdgcn_global_load_lds((ga_u32*)(gp3b + kt),
                                         (ls_u32*)(b + 4096 + wave * 512), 16, 0, 1);     // sc0
        __builtin_amdgcn_global_load_lds((ga_u32*)(gp3b + kt + 32),
                                         (ls_u32*)(b + 6144 + wave * 512), 16, 0, 1);     // sc0
      };
      auto cmp3 = [&](int slot) {
        const u16* b = S3 + slot * 8192;
#pragma unroll
        for (int ks = 0; ks < 2; ++ks) {
          s16x8 af[2], bf[2];
#pragma unroll
          for (int i = 0; i < 2; ++i)
            af[i] = *(const s16x8*)(b + ks * 2048 + (wm * 32 + i * 16 + r16) * 32 + cqa);
#pragma unroll
          for (int j = 0; j < 2; ++j)
            bf[j] = *(const s16x8*)(b + 4096 + ks * 2048 + (wn * 32 + j * 16 + r16) * 32 + cqa);
#pragma unroll
          for (int i = 0; i < 2; ++i)
#pragma unroll
            for (int j = 0; j < 2; ++j)
              a3[i][j] = __builtin_amdgcn_mfma_f32_16x16x32_bf16(af[i], bf[j], a3[i][j], 0, 0, 0);
        }
      };

      // 4-slot ring, 3 ahead: 12 outstanding/wave; vmcnt(8) completes oldest 4.
      stg3(0, 0); stg3(64, 1); stg3(128, 2);
      for (int it = 0; it < 16; ++it) {
        if (it < 14)        asm volatile("s_waitcnt vmcnt(8)" ::: "memory");
        else if (it == 14)  asm volatile("s_waitcnt vmcnt(4)" ::: "memory");
        else                asm volatile("s_waitcnt vmcnt(0)" ::: "memory");
        __builtin_amdgcn_s_barrier();
        if (it + 3 < 16) stg3((it + 3) * 64, (it + 3) & 3);
        cmp3(it & 3);
      }

      if (bh == 0 && tid < 64) {           // apply clipped div to lp; reset accumulators
        int b = row0 + tid;
        float c0 = __hip_atomic_load(&div0[b], __ATOMIC_RELAXED, __HIP_MEMORY_SCOPE_AGENT);
        float c1 = __hip_atomic_load(&div1[b], __ATOMIC_RELAXED, __HIP_MEMORY_SCOPE_AGENT);
        float c = 0.5f * (c0 + c1);
        c = fminf(fmaxf(c, -100.f), 100.f);
        lp[b] -= wdt * c;
        div0[b] = 0.f; div1[b] = 0.f;
      }

      // RK38 epilogue — state in LDS; zin (bf16) is the only global output.
#pragma unroll
      for (int j = 0; j < 2; ++j) {
        const int gcol = col0 + wn * 32 + j * 16 + r16;
        const float cb = b2v[gcol];
#pragma unroll
        for (int i = 0; i < 2; ++i) {
          const int rbase = row0 + wm * 32 + i * 16 + q * 4;
#pragma unroll
          for (int rr = 0; rr < 4; ++rr) {
            const size_t idx2 = (size_t)(rbase + rr) * D_N + gcol;
            const int si = ST_IDX(i, rr, j);
            const float f = a3[i][j][rr] + cb;
            if (rsub == 0) {
              STa[si] = dtt * 0.125f * f;
              STt[si] = dtt * f;
              zin[idx2] = f2bf(STz[si] + dtt * f * (1.f / 3.f));
            } else if (rsub == 1) {
              float t_ = STt[si];
              STa[si] += 0.375f * dtt * f;
              zin[idx2] = f2bf(STz[si] + dtt * f - t_ * (1.f / 3.f));
              STt[si] = t_ - dtt * f;
            } else if (rsub == 2) {
              STa[si] += 0.375f * dtt * f;
              zin[idx2] = f2bf(STz[si] + STt[si] + dtt * f);
            } else {
              float zn = STz[si] + STa[si] + dtt * 0.125f * f;
              STz[si] = zn;
              zin[idx2] = f2bf(zn);
            }
          }
        }
      }

      // regen e for stage st+4 into the slot f1(st) just freed (slab-local).
      if (st + 4 < 36) egen_unit(st + 4, bh * 256 + tid);
    }
    tgt += 8; slab_bar(ctr, tgt);
  }

  // ================= out phase: rep from LDS state + logprob =================
  // rep write + per-row partial ss -> div0 (zeroed at st=35) via atomics.
#pragma unroll
  for (int i = 0; i < 2; ++i) {
#pragma unroll
    for (int rr = 0; rr < 4; ++rr) {
      const int grow = row0 + wm * 32 + i * 16 + q * 4 + rr;
      float val = 0.f;
#pragma unroll
      for (int j = 0; j < 2; ++j) {
        const int gcol = bh * 64 + wn * 32 + j * 16 + r16;
        const float v = STz[ST_IDX(i, rr, j)];
        outp[(size_t)grow * D_N + gcol] = v;
        val += v * v;
      }
#pragma unroll
      for (int m = 1; m < 16; m <<= 1) val += __shfl_xor(val, m);
      if (r16 == 0) atomicAdd(&div0[grow], val);
    }
  }
  tgt += 8; slab_bar(ctr, tgt);
  if (bh == 0 && tid < 64) {
    const int b = row0 + tid;
    float ss = __hip_atomic_load(&div0[b], __ATOMIC_RELAXED, __HIP_MEMORY_SCOPE_AGENT);
    float lpv = __hip_atomic_load(&lp[b], __ATOMIC_RELAXED, __HIP_MEMORY_SCOPE_AGENT);
    outp[(size_t)BD + b] = -0.5f * ss + lpv;
  }
#undef ST_IDX
}

extern "C" void kernel_launch(void* const* d_in, const int* in_sizes, int n_in,
                              void* d_out, int out_size, void* d_ws, size_t ws_size,
                              hipStream_t stream) {
  const float* x   = (const float*)d_in[0];
  const float* W1  = (const float*)d_in[1];
  const float* b1  = (const float*)d_in[2];
  const float* tw1 = (const float*)d_in[3];
  const float* W2  = (const float*)d_in[4];
  const float* b2  = (const float*)d_in[5];
  float* outp = (float*)d_out;

  const size_t NEEDED = (size_t)45 << 20;
  if (ws_size < NEEDED) {
    k_sentinel<<<(BD + B_N + 255) / 256, 256, 0, stream>>>(outp, BD + B_N);
    return;
  }
  char* w = (char*)d_ws;
  auto carve = [&](size_t bytes) { char* p = w; w += (bytes + 255) & ~(size_t)255; return p; };
  uint32_t* keys = (uint32_t*)carve(144 * sizeof(uint32_t));
  u16* ebf   = (u16*)carve((size_t)4 * 2 * BD * 2);               // 16 MB: 4-slot e ring
  u16* zin   = (u16*)carve((size_t)BD * 2);
  u16* hbuf  = (u16*)carve((size_t)B_N * H_N * 2);
  u16* W1T   = (u16*)carve((size_t)H_N * D_N * 2);
  u16* W2b   = (u16*)carve((size_t)H_N * D_N * 2);
  u16* W2T   = (u16*)carve((size_t)D_N * H_N * 2);
  float* lp   = (float*)carve((size_t)B_N * 4);
  float* div0 = (float*)carve((size_t)B_N * 4);
  float* div1 = (float*)carve((size_t)B_N * 4);
  uint32_t* barv = (uint32_t*)carve(4096);       // 32 slab counters, 128B stride

  k_keysched<<<1, 1, 0, stream>>>(keys);
  k_init<<<BD / 256, 256, 0, stream>>>(x, zin, lp, div0, div1, barv);
  k_cvtT<<<(D_N * H_N) / 256, 256, 0, stream>>>(W1, W1T, D_N, H_N);
  k_cvt <<<(H_N * D_N) / 256, 256, 0, stream>>>(W2, W2b, H_N * D_N);
  k_cvtT<<<(H_N * D_N) / 256, 256, 0, stream>>>(W2, W2T, H_N, D_N);

  k_fused<<<256, 256, 0, stream>>>(keys, ebf, x, zin, W1T, W2b, W2T, b1, tw1, b2,
                                   hbuf, lp, div0, div1, barv, outp);
}

// Round 9
// 1456.304 us; speedup vs baseline: 1.3887x; 1.3887x over previous
//
#include <hip/hip_runtime.h>
#include <stdint.h>

// FFJORD block: B=2048, D=512, H=1024, 9 RK38 steps x 4 stages, 2 Hutchinson probes.
// f32 in/out. bf16 MFMA GEMMs, f32 accumulate, fp32 RK state.
// PRNG: JAX threefry partitionable (verified R7).
// R23: 2 blocks/CU TLP. R21/R22 post-mortem: local state (reg AND LDS) both
// regressed; R19 (global state, fence-free) remains best at 1414us with
// MfmaUtil 13.7 / VALU 23 / HBM 15 / occupancy 12% => ~60% idle in all pipes
// = latency-bound with zero TLP (1 block/CU, 1 wave/SIMD). Fix: grid 512
// (32 slabs x 16 col-blocks), f1 64x64 tile (acc 160->80 VGPR, no spill),
// ring 4x20KB=80KB LDS => exactly 2 blocks/CU; launch_bounds(256,2).
// f3 = R18 64x32 K32 shape with per-wave-correct vmcnt. State z/ACC/T in
// global (R19). 16-way slab barriers, fence-free + sc0 (R19 protocol).
// egen split to 16-elem tasks (identical counter->elem map).

#define B_N 2048
#define D_N 512
#define H_N 1024
#define BD (B_N * D_N)

typedef unsigned short u16;
typedef __attribute__((ext_vector_type(8))) short s16x8;   // 8 x bf16
typedef __attribute__((ext_vector_type(4))) float f32x4;   // MFMA accumulator

typedef __attribute__((address_space(1))) const uint32_t ga_u32;
typedef __attribute__((address_space(3))) uint32_t ls_u32;

#if __has_builtin(__builtin_amdgcn_alignbit)
#define ROTL32(x, r) __builtin_amdgcn_alignbit((x), (x), 32 - (r))
#else
#define ROTL32(x, r) (((x) << (r)) | ((x) >> (32 - (r))))
#endif

__device__ __forceinline__ u16 f2bf(float f) {
  union { float f; uint32_t u; } c; c.f = f;
  uint32_t r = c.u + 0x7FFFu + ((c.u >> 16) & 1u);  // RTNE
  return (u16)(r >> 16);
}
__device__ __forceinline__ float fast_tanh(float v) {
  float e = __expf(2.0f * fabsf(v));
  float t = 1.0f - 2.0f / (e + 1.0f);
  return copysignf(t, v);
}

struct U2 { uint32_t x, y; };

// Threefry-2x32, 20 rounds — KAT-verified.
__device__ __forceinline__ U2 tf2x32(uint32_t k0, uint32_t k1, uint32_t x0, uint32_t x1) {
  uint32_t k2 = k0 ^ k1 ^ 0x1BD11BDAu;
#define RND(r) { x0 += x1; x1 = ROTL32(x1, r); x1 ^= x0; }
  x0 += k0; x1 += k1;
  RND(13) RND(15) RND(26) RND(6)
  x0 += k1; x1 += k2 + 1u;
  RND(17) RND(29) RND(16) RND(24)
  x0 += k2; x1 += k0 + 2u;
  RND(13) RND(15) RND(26) RND(6)
  x0 += k0; x1 += k1 + 3u;
  RND(17) RND(29) RND(16) RND(24)
  x0 += k1; x1 += k2 + 4u;
  RND(13) RND(15) RND(26) RND(6)
  x0 += k2; x1 += k0 + 5u;
#undef RND
  U2 r; r.x = x0; r.y = x1; return r;
}

// Partitionable key schedule (verified R7).
__global__ void k_keysched(uint32_t* __restrict__ ekeys) {
  if (threadIdx.x != 0 || blockIdx.x != 0) return;
  uint32_t kx = 0u, ky = 1234u;
  for (int s = 0; s < 9; ++s) {
    for (int st = 0; st < 4; ++st) {
      U2 kst = tf2x32(kx, ky, 0u, (uint32_t)(st + 1));
      for (int pr = 0; pr < 2; ++pr) {
        U2 fo = tf2x32(kst.x, kst.y, 0u, (uint32_t)pr);
        U2 k2 = tf2x32(fo.x, fo.y, 0u, 1u);
        ekeys[(s * 4 + st) * 4 + pr * 2 + 0] = k2.x;
        ekeys[(s * 4 + st) * 4 + pr * 2 + 1] = k2.y;
      }
    }
    U2 c = tf2x32(kx, ky, 0u, 0u);
    kx = c.x; ky = c.y;
  }
}

__global__ void k_init(const float* __restrict__ x, float* __restrict__ z, u16* __restrict__ zin,
                       float* __restrict__ lp, float* __restrict__ d0, float* __restrict__ d1,
                       uint32_t* __restrict__ barv) {
  int i = blockIdx.x * 256 + threadIdx.x;
  if (i < BD) { float v = x[i]; z[i] = v; zin[i] = f2bf(v); }
  if (i < B_N) { lp[i] = 0.f; d0[i] = 0.f; d1[i] = 0.f; }
  if (i < 1024) barv[i] = 0u;                    // 32 slab counters, 128B stride
}

__global__ void k_cvtT(const float* __restrict__ src, u16* __restrict__ dst, int R, int C) {
  int i = blockIdx.x * 256 + threadIdx.x;
  if (i >= R * C) return;
  int c = i / R, r = i - c * R;
  dst[i] = f2bf(src[(size_t)r * C + c]);
}
__global__ void k_cvt(const float* __restrict__ src, u16* __restrict__ dst, int n) {
  int i = blockIdx.x * 256 + threadIdx.x;
  if (i < n) dst[i] = f2bf(src[i]);
}

__global__ void k_sentinel(float* __restrict__ out, int n) {
  int i = blockIdx.x * 256 + threadIdx.x;
  if (i < n) out[i] = 12345.0f;
}

// 16-way slab barrier, fence-free (monotonic counter, re-zeroed each replay).
// All 16 participants share one XCD L2 (coherence point): L1 write-through,
// atomics at L2; producers drain vmcnt before RELAXED signal, consumers use
// sc0 loads / L2 atomics. No buffer_wbl2 / buffer_inv.
__device__ __forceinline__ void slab_bar(uint32_t* ctr, uint32_t tgt) {
  asm volatile("s_waitcnt vmcnt(0)" ::: "memory");
  __syncthreads();
  if (threadIdx.x == 0) {
    __hip_atomic_fetch_add(ctr, 1u, __ATOMIC_RELAXED, __HIP_MEMORY_SCOPE_AGENT);
    while (__hip_atomic_load(ctr, __ATOMIC_RELAXED, __HIP_MEMORY_SCOPE_AGENT) < tgt)
      __builtin_amdgcn_s_sleep(1);
  }
  __syncthreads();
}

// LDS chunk swizzle (R13-verified): chunk c of 16-row-group row r at chunk c^((r>>1)&3).
// f1: 64x64 block tile, 4 waves of 32x32, K=512, 16 K-steps, 4-ring vmcnt(10).
//     Staging: 20 slots of 512 u16, slot s = li*4+wave, LDS off s*512:
//     s<12: A {zin,e0,e1}=s>>2, part s&3; s>=12: B {W1T,W2b}=(s-12)>>2, part (s-12)&3.
// f3: 64x32 block tile, 4 waves, K=1024, 32 K-steps, 4-ring, per-wave vmcnt.
__global__ __launch_bounds__(256, 2)
void k_fused(const uint32_t* __restrict__ keys, u16* __restrict__ ebf,
             u16* __restrict__ zin,
             const u16* __restrict__ W1T, const u16* __restrict__ W2b, const u16* __restrict__ W2T,
             const float* __restrict__ b1v, const float* __restrict__ tw1v, const float* __restrict__ b2v,
             float* __restrict__ z, float* __restrict__ ACC, float* __restrict__ T,
             u16* __restrict__ hbuf,
             float* __restrict__ lp, float* __restrict__ div0, float* __restrict__ div1,
             uint32_t* __restrict__ barv, float* __restrict__ outp) {
  __shared__ u16 S[4][10240];   // 80KB: f1 ring [zin|e0|e1|W1|W2] x4; f3 ring aliased at base
  const int tid = threadIdx.x, wave = tid >> 6, lane = tid & 63;
  const int xcd = blockIdx.x & 7, idx = blockIdx.x >> 3;   // 512 blocks: 64/XCD
  const int bm = xcd * 4 + (idx >> 4);       // row-slab of 64, pinned to XCD
  const int bh = idx & 15;                   // f1: col-block of 64 (H); f3: col-block of 32 (D)
  const int row0 = bm * 64;
  const int wm = wave >> 1, wn = wave & 1, r16 = lane & 15, q = lane >> 4;
  const int srow = lane >> 2;
  const int scol = (((lane & 3) ^ ((srow >> 1) & 3))) * 8;   // swizzled source chunk
  const int cqa = (q ^ ((r16 >> 1) & 3)) * 8;                // swizzled read chunk

  uint32_t* ctr = barv + bm * 32;            // this slab's barrier counter
  uint32_t tgt = 0;

  // ---- egen: one (stage, 16-elem task) per call; slab-local.
  // t in [0,4096): probe = t>>11, e16 = t&2047; counters = elem indices (as before).
  auto egen_unit = [&](int stg, int t) {
    const int probe = t >> 11, e16 = t & 2047;
    const uint32_t p0 = (uint32_t)(bm * 32768 + e16 * 16);
    uint32_t k0 = keys[stg * 4 + probe * 2], k1 = keys[stg * 4 + probe * 2 + 1];
    uint4* dst = (uint4*)(ebf + (size_t)(stg & 3) * (2 * (size_t)BD) + (size_t)probe * BD + (size_t)p0);
#pragma unroll
    for (int g = 0; g < 2; ++g) {
      uint32_t pr[4];
#pragma unroll
      for (int h = 0; h < 4; ++h) {
        uint32_t c0 = p0 + g * 8 + h * 2;
        U2 r0 = tf2x32(k0, k1, 0u, c0);
        U2 r1 = tf2x32(k0, k1, 0u, c0 + 1u);
        pr[h] = (((r0.x ^ r0.y) & 1u) ? 0x3F80u : 0xBF80u) |
                (((r1.x ^ r1.y) & 1u) ? 0x3F800000u : 0xBF800000u);
      }
      uint4 v; v.x = pr[0]; v.y = pr[1]; v.z = pr[2]; v.w = pr[3];
      dst[g] = v;
    }
  };

  // Prologue: e for stages 0..3 of this slab (4096 threads x 1 task each).
#pragma unroll
  for (int r = 0; r < 4; ++r) egen_unit(r, bh * 256 + tid);
  tgt += 16; slab_bar(ctr, tgt);

  for (int st = 0; st < 36; ++st) {
    const int s9 = st >> 2, rsub = st & 3;
    const float t0f = (float)s9 / 9.0f;
    const float t1f = (float)(s9 + 1) / 9.0f;
    const float dtt = t1f - t0f;
    const float tstage = (rsub == 0) ? t0f : (rsub == 1) ? (t0f + dtt / 3.0f)
                       : (rsub == 2) ? (t0f + dtt * 2.0f / 3.0f) : t1f;
    const float wdt = dtt * 0.125f * ((rsub == 1 || rsub == 2) ? 3.0f : 1.0f);

    // ================= f1 phase (64x64, 4 waves of 32x32) =================
    {
      const u16* e0g = ebf + (size_t)(st & 3) * (2 * (size_t)BD);
      const u16* e1g = e0g + BD;
      const int col0 = bh * 64;

      f32x4 az[2][2], au0[2][2], au1[2][2], av0[2][2], av1[2][2];
#pragma unroll
      for (int i = 0; i < 2; ++i)
#pragma unroll
        for (int j = 0; j < 2; ++j) {
          az[i][j] = (f32x4){0,0,0,0}; au0[i][j] = (f32x4){0,0,0,0}; au1[i][j] = (f32x4){0,0,0,0};
          av0[i][j] = (f32x4){0,0,0,0}; av1[i][j] = (f32x4){0,0,0,0};
        }

      const u16* gp[5];
#pragma unroll
      for (int li = 0; li < 5; ++li) {
        const int s = li * 4 + wave;
        const u16* base;
        int row;
        if (s < 12) {
          const int mat = s >> 2;
          base = (mat == 0) ? zin : (mat == 1) ? e0g : e1g;
          row = row0 + (s & 3) * 16 + srow;
        } else {
          const int t = s - 12;
          base = (t < 4) ? W1T : W2b;
          row = col0 + (t & 3) * 16 + srow;
        }
        gp[li] = base + (size_t)row * 512 + scol;
      }

      auto stg1 = [&](int kt, int slot) {
        u16* b = &S[slot][0];
#pragma unroll
        for (int li = 0; li < 5; ++li)
          __builtin_amdgcn_global_load_lds((ga_u32*)(gp[li] + kt),
                                           (ls_u32*)(b + (li * 4 + wave) * 512), 16, 0, 1); // sc0
      };
      auto cmp1 = [&](int slot) {
        const u16* b = &S[slot][0];
        s16x8 zf[2], e0f[2], e1f[2], w1f[2], w2f[2];
#pragma unroll
        for (int i = 0; i < 2; ++i) {
          const int ao = (wm * 32 + i * 16 + r16) * 32 + cqa;
          zf[i]  = *(const s16x8*)(b + 0    + ao);
          e0f[i] = *(const s16x8*)(b + 2048 + ao);
          e1f[i] = *(const s16x8*)(b + 4096 + ao);
        }
#pragma unroll
        for (int j = 0; j < 2; ++j) {
          const int bo = (wn * 32 + j * 16 + r16) * 32 + cqa;
          w1f[j] = *(const s16x8*)(b + 6144 + bo);
          w2f[j] = *(const s16x8*)(b + 8192 + bo);
        }
#pragma unroll
        for (int i = 0; i < 2; ++i)
#pragma unroll
          for (int j = 0; j < 2; ++j) {
            az[i][j]  = __builtin_amdgcn_mfma_f32_16x16x32_bf16(zf[i],  w1f[j], az[i][j],  0, 0, 0);
            au0[i][j] = __builtin_amdgcn_mfma_f32_16x16x32_bf16(e0f[i], w1f[j], au0[i][j], 0, 0, 0);
            au1[i][j] = __builtin_amdgcn_mfma_f32_16x16x32_bf16(e1f[i], w1f[j], au1[i][j], 0, 0, 0);
            av0[i][j] = __builtin_amdgcn_mfma_f32_16x16x32_bf16(e0f[i], w2f[j], av0[i][j], 0, 0, 0);
            av1[i][j] = __builtin_amdgcn_mfma_f32_16x16x32_bf16(e1f[i], w2f[j], av1[i][j], 0, 0, 0);
          }
      };

      // 4-slot ring, 3 ahead: 15 outstanding/wave; vmcnt(10) completes oldest 5.
      stg1(0, 0); stg1(32, 1); stg1(64, 2);
      for (int it = 0; it < 16; ++it) {
        if (it < 14)        asm volatile("s_waitcnt vmcnt(10)" ::: "memory");
        else if (it == 14)  asm volatile("s_waitcnt vmcnt(5)" ::: "memory");
        else                asm volatile("s_waitcnt vmcnt(0)" ::: "memory");
        __builtin_amdgcn_s_barrier();
        if (it + 3 < 16) stg1((it + 3) * 32, (it + 3) & 3);
        cmp1(it & 3);
      }

      float d0s[2][4], d1s[2][4];
#pragma unroll
      for (int i = 0; i < 2; ++i)
#pragma unroll
        for (int rr = 0; rr < 4; ++rr) { d0s[i][rr] = 0.f; d1s[i][rr] = 0.f; }

#pragma unroll
      for (int j = 0; j < 2; ++j) {
        const int gcol = col0 + wn * 32 + j * 16 + r16;
        const float colb = b1v[gcol] + tstage * tw1v[gcol];
#pragma unroll
        for (int i = 0; i < 2; ++i) {
          const int rbase = row0 + wm * 32 + i * 16 + q * 4;   // C/D: row=quad*4+reg
#pragma unroll
          for (int rr = 0; rr < 4; ++rr) {
            float hv = fast_tanh(az[i][j][rr] + colb);
            hbuf[(size_t)(rbase + rr) * H_N + gcol] = f2bf(hv);
            float sd = 1.f - hv * hv;
            d0s[i][rr] += sd * au0[i][j][rr] * av0[i][j][rr];
            d1s[i][rr] += sd * au1[i][j][rr] * av1[i][j][rr];
          }
        }
      }
#pragma unroll
      for (int i = 0; i < 2; ++i)
#pragma unroll
        for (int rr = 0; rr < 4; ++rr) {
          float a = d0s[i][rr], bb = d1s[i][rr];
#pragma unroll
          for (int m = 1; m < 16; m <<= 1) { a += __shfl_xor(a, m); bb += __shfl_xor(bb, m); }
          if (r16 == 0) {
            int grow = row0 + wm * 32 + i * 16 + q * 4 + rr;
            atomicAdd(&div0[grow], a);
            atomicAdd(&div1[grow], bb);
          }
        }
    }
    tgt += 16; slab_bar(ctr, tgt);

    // ================= f3 phase (64x32; + lp/div apply, + egen st+4) =================
    {
      const int col0 = bh * 32;
      u16* S3 = &S[0][0];      // 4 ring slots of 3072 u16: [A 2048 | B 1024]

      f32x4 acc[2];
      acc[0] = (f32x4){0,0,0,0}; acc[1] = (f32x4){0,0,0,0};

      const u16* gp3a = hbuf + (size_t)(row0 + wave * 16 + srow) * 1024 + scol;
      const u16* gp3b = W2T  + (size_t)(col0 + (wave & 1) * 16 + srow) * 1024 + scol;

      // waves 0-1: 2 loads/step (A+B); waves 2-3: 1 load/step (A).
      auto stg3 = [&](int kt, int slot) {
        u16* b = S3 + slot * 3072;
        __builtin_amdgcn_global_load_lds((ga_u32*)(gp3a + kt),
                                         (ls_u32*)(b + wave * 512), 16, 0, 1);            // sc0
        if (wave < 2)
          __builtin_amdgcn_global_load_lds((ga_u32*)(gp3b + kt),
                                           (ls_u32*)(b + 2048 + wave * 512), 16, 0, 1);   // sc0
      };
      auto cmp3 = [&](int slot) {
        const u16* b = S3 + slot * 3072;
        s16x8 af  = *(const s16x8*)(b + (wave * 16 + r16) * 32 + cqa);
        s16x8 bf0 = *(const s16x8*)(b + 2048 + r16 * 32 + cqa);
        s16x8 bf1 = *(const s16x8*)(b + 2048 + (16 + r16) * 32 + cqa);
        acc[0] = __builtin_amdgcn_mfma_f32_16x16x32_bf16(af, bf0, acc[0], 0, 0, 0);
        acc[1] = __builtin_amdgcn_mfma_f32_16x16x32_bf16(af, bf1, acc[1], 0, 0, 0);
      };

      stg3(0, 0); stg3(32, 1); stg3(64, 2);

      if (bh == 0 && tid < 64) {           // apply clipped div to lp; reset accumulators
        int b = row0 + tid;
        float c0 = __hip_atomic_load(&div0[b], __ATOMIC_RELAXED, __HIP_MEMORY_SCOPE_AGENT);
        float c1 = __hip_atomic_load(&div1[b], __ATOMIC_RELAXED, __HIP_MEMORY_SCOPE_AGENT);
        float c = 0.5f * (c0 + c1);
        c = fminf(fmaxf(c, -100.f), 100.f);
        lp[b] -= wdt * c;
        div0[b] = 0.f; div1[b] = 0.f;
      }

      // 4-slot ring, 3 ahead; per-wave counted vmcnt (w0-1: 2/step, w2-3: 1/step).
      for (int it = 0; it < 32; ++it) {
        if (it < 30) {
          if (wave < 2) asm volatile("s_waitcnt vmcnt(4)" ::: "memory");
          else          asm volatile("s_waitcnt vmcnt(2)" ::: "memory");
        } else if (it == 30) {
          if (wave < 2) asm volatile("s_waitcnt vmcnt(2)" ::: "memory");
          else          asm volatile("s_waitcnt vmcnt(1)" ::: "memory");
        } else {
          asm volatile("s_waitcnt vmcnt(0)" ::: "memory");
        }
        __builtin_amdgcn_s_barrier();
        if (it + 3 < 32) stg3((it + 3) * 32, (it + 3) & 3);
        cmp3(it & 3);
      }

      // RK38 epilogue (global z/ACC/T — block-private tiles).
#pragma unroll
      for (int j = 0; j < 2; ++j) {
        const int gcol = col0 + j * 16 + r16;
        const float cb = b2v[gcol];
        const int rbase = row0 + wave * 16 + q * 4;
#pragma unroll
        for (int rr = 0; rr < 4; ++rr) {
          const size_t idx2 = (size_t)(rbase + rr) * D_N + gcol;
          const float f = acc[j][rr] + cb;
          if (rsub == 0) {
            ACC[idx2] = dtt * 0.125f * f;
            T[idx2]   = dtt * f;
            zin[idx2] = f2bf(z[idx2] + dtt * f * (1.f / 3.f));
          } else if (rsub == 1) {
            float t_ = T[idx2];
            ACC[idx2] += 0.375f * dtt * f;
            zin[idx2] = f2bf(z[idx2] + dtt * f - t_ * (1.f / 3.f));
            T[idx2]   = t_ - dtt * f;
          } else if (rsub == 2) {
            ACC[idx2] += 0.375f * dtt * f;
            zin[idx2] = f2bf(z[idx2] + T[idx2] + dtt * f);
          } else {
            float zn = z[idx2] + ACC[idx2] + dtt * 0.125f * f;
            z[idx2]   = zn;
            zin[idx2] = f2bf(zn);
          }
        }
      }

      // regen e for stage st+4 into the slot f1(st) just freed (slab-local).
      if (st + 4 < 36) egen_unit(st + 4, bh * 256 + tid);
    }
    tgt += 16; slab_bar(ctr, tgt);
  }

  // ================= out phase: one wave per row =================
  {
    const int b = row0 + bh * 4 + wave;
    const float* zr = z + (size_t)b * D_N + lane * 8;
    float4 v0 = *(const float4*)zr;
    float4 v1 = *(const float4*)(zr + 4);
    *(float4*)(outp + (size_t)b * D_N + lane * 8)     = v0;
    *(float4*)(outp + (size_t)b * D_N + lane * 8 + 4) = v1;
    float ss = v0.x*v0.x + v0.y*v0.y + v0.z*v0.z + v0.w*v0.w
             + v1.x*v1.x + v1.y*v1.y + v1.z*v1.z + v1.w*v1.w;
#pragma unroll
    for (int m = 1; m < 64; m <<= 1) ss += __shfl_xor(ss, m);
    if (lane == 0) {
      float lpv = __hip_atomic_load(&lp[b], __ATOMIC_RELAXED, __HIP_MEMORY_SCOPE_AGENT);
      outp[(size_t)BD + b] = -0.5f * ss + lpv;
    }
  }
}

extern "C" void kernel_launch(void* const* d_in, const int* in_sizes, int n_in,
                              void* d_out, int out_size, void* d_ws, size_t ws_size,
                              hipStream_t stream) {
  const float* x   = (const float*)d_in[0];
  const float* W1  = (const float*)d_in[1];
  const float* b1  = (const float*)d_in[2];
  const float* tw1 = (const float*)d_in[3];
  const float* W2  = (const float*)d_in[4];
  const float* b2  = (const float*)d_in[5];
  float* outp = (float*)d_out;

  const size_t NEEDED = (size_t)45 << 20;
  if (ws_size < NEEDED) {
    k_sentinel<<<(BD + B_N + 255) / 256, 256, 0, stream>>>(outp, BD + B_N);
    return;
  }
  char* w = (char*)d_ws;
  auto carve = [&](size_t bytes) { char* p = w; w += (bytes + 255) & ~(size_t)255; return p; };
  uint32_t* keys = (uint32_t*)carve(144 * sizeof(uint32_t));
  u16* ebf   = (u16*)carve((size_t)4 * 2 * BD * 2);               // 16 MB: 4-slot e ring
  float* z   = (float*)carve((size_t)BD * 4);
  float* ACC = (float*)carve((size_t)BD * 4);
  float* T   = (float*)carve((size_t)BD * 4);
  u16* zin   = (u16*)carve((size_t)BD * 2);
  u16* hbuf  = (u16*)carve((size_t)B_N * H_N * 2);
  u16* W1T   = (u16*)carve((size_t)H_N * D_N * 2);
  u16* W2b   = (u16*)carve((size_t)H_N * D_N * 2);
  u16* W2T   = (u16*)carve((size_t)D_N * H_N * 2);
  float* lp   = (float*)carve((size_t)B_N * 4);
  float* div0 = (float*)carve((size_t)B_N * 4);
  float* div1 = (float*)carve((size_t)B_N * 4);
  uint32_t* barv = (uint32_t*)carve(4096);       // 32 slab counters, 128B stride

  k_keysched<<<1, 1, 0, stream>>>(keys);
  k_init<<<BD / 256, 256, 0, stream>>>(x, z, zin, lp, div0, div1, barv);
  k_cvtT<<<(D_N * H_N) / 256, 256, 0, stream>>>(W1, W1T, D_N, H_N);
  k_cvt <<<(H_N * D_N) / 256, 256, 0, stream>>>(W2, W2b, H_N * D_N);
  k_cvtT<<<(H_N * D_N) / 256, 256, 0, stream>>>(W2, W2T, H_N, D_N);

  k_fused<<<512, 256, 0, stream>>>(keys, ebf, zin, W1T, W2b, W2T, b1, tw1, b2,
                                   z, ACC, T, hbuf, lp, div0, div1, barv, outp);
}

// Round 10
// 1402.059 us; speedup vs baseline: 1.4425x; 1.0387x over previous
//
#include <hip/hip_runtime.h>
#include <stdint.h>

// FFJORD block: B=2048, D=512, H=1024, 9 RK38 steps x 4 stages, 2 Hutchinson probes.
// f32 in/out. bf16 MFMA GEMMs, f32 accumulate, fp32 RK state.
// PRNG: JAX threefry partitionable (verified R7).
// R24: best-of synthesis. Fusion arc (R17-R23) established: time ~1400us is
// invariant to sync structure, staged bytes, FETCH, pipeline depth, occupancy,
// state placement => structure floor (L2->CU + LDS wr+rd operand flows +
// MFMA, comparable and partially serialized), not a single-pipe roofline.
// Fused never beat multi-kernel (best fused 1410 vs multi 1401). So: revert
// to the R14 multi-kernel structure and bank the one transferable win:
// egen folded into k_f3 (R18 balanced form, 16 elems/thread) — deletes 8 of
// 9 egen dispatches from the serial chain; threefry VALU hides under f3's
// epilogue. Slot timing safe by stream order: f3(sg) writes slot (sg+4)&3 =
// sg&3, last read by already-retired f1(sg).

#define B_N 2048
#define D_N 512
#define H_N 1024
#define BD (B_N * D_N)

typedef unsigned short u16;
typedef __attribute__((ext_vector_type(8))) short s16x8;   // 8 x bf16
typedef __attribute__((ext_vector_type(4))) float f32x4;   // MFMA accumulator

typedef __attribute__((address_space(1))) const uint32_t ga_u32;
typedef __attribute__((address_space(3))) uint32_t ls_u32;

#if __has_builtin(__builtin_amdgcn_alignbit)
#define ROTL32(x, r) __builtin_amdgcn_alignbit((x), (x), 32 - (r))
#else
#define ROTL32(x, r) (((x) << (r)) | ((x) >> (32 - (r))))
#endif

__device__ __forceinline__ u16 f2bf(float f) {
  union { float f; uint32_t u; } c; c.f = f;
  uint32_t r = c.u + 0x7FFFu + ((c.u >> 16) & 1u);  // RTNE
  return (u16)(r >> 16);
}
__device__ __forceinline__ float fast_tanh(float v) {
  float e = __expf(2.0f * fabsf(v));
  float t = 1.0f - 2.0f / (e + 1.0f);
  return copysignf(t, v);
}

struct U2 { uint32_t x, y; };

// Threefry-2x32, 20 rounds — KAT-verified.
__device__ __forceinline__ U2 tf2x32(uint32_t k0, uint32_t k1, uint32_t x0, uint32_t x1) {
  uint32_t k2 = k0 ^ k1 ^ 0x1BD11BDAu;
#define RND(r) { x0 += x1; x1 = ROTL32(x1, r); x1 ^= x0; }
  x0 += k0; x1 += k1;
  RND(13) RND(15) RND(26) RND(6)
  x0 += k1; x1 += k2 + 1u;
  RND(17) RND(29) RND(16) RND(24)
  x0 += k2; x1 += k0 + 2u;
  RND(13) RND(15) RND(26) RND(6)
  x0 += k0; x1 += k1 + 3u;
  RND(17) RND(29) RND(16) RND(24)
  x0 += k1; x1 += k2 + 4u;
  RND(13) RND(15) RND(26) RND(6)
  x0 += k2; x1 += k0 + 5u;
#undef RND
  U2 r; r.x = x0; r.y = x1; return r;
}

// Partitionable key schedule (verified R7).
__global__ void k_keysched(uint32_t* __restrict__ ekeys) {
  if (threadIdx.x != 0 || blockIdx.x != 0) return;
  uint32_t kx = 0u, ky = 1234u;
  for (int s = 0; s < 9; ++s) {
    for (int st = 0; st < 4; ++st) {
      U2 kst = tf2x32(kx, ky, 0u, (uint32_t)(st + 1));
      for (int pr = 0; pr < 2; ++pr) {
        U2 fo = tf2x32(kst.x, kst.y, 0u, (uint32_t)pr);
        U2 k2 = tf2x32(fo.x, fo.y, 0u, 1u);
        ekeys[(s * 4 + st) * 4 + pr * 2 + 0] = k2.x;
        ekeys[(s * 4 + st) * 4 + pr * 2 + 1] = k2.y;
      }
    }
    U2 c = tf2x32(kx, ky, 0u, 0u);
    kx = c.x; ky = c.y;
  }
}

// Fused threefry + bf16 expansion for 4 stages, XCD-affine (prologue only).
__global__ void k_egen(u16* __restrict__ ebf, const uint32_t* __restrict__ keys, int gs) {
  const int xcd = blockIdx.x & 7, bi = blockIdx.x >> 3;      // 1024 blocks: 128/XCD
  const int u = bi * 256 + threadIdx.x;                       // 0..32767 per XCD
  const int slab = xcd * 4 + (u >> 13);
  const int r13 = u & 8191;
  const int stage = gs + (r13 >> 11);
  const int r11 = r13 & 2047;
  const int probe = r11 >> 10;
  const int unit = r11 & 1023;                                // 1024 units/slab
  const uint32_t p0 = (uint32_t)(slab * 32768 + unit * 32);
  uint32_t k0 = keys[stage * 4 + probe * 2], k1 = keys[stage * 4 + probe * 2 + 1];
  uint4* dst = (uint4*)(ebf + (size_t)(stage & 3) * (2 * (size_t)BD) + (size_t)probe * BD + (size_t)p0);
#pragma unroll
  for (int g = 0; g < 4; ++g) {
    uint32_t pr[4];
#pragma unroll
    for (int h = 0; h < 4; ++h) {
      uint32_t c0 = p0 + g * 8 + h * 2;
      U2 r0 = tf2x32(k0, k1, 0u, c0);
      U2 r1 = tf2x32(k0, k1, 0u, c0 + 1u);
      pr[h] = (((r0.x ^ r0.y) & 1u) ? 0x3F80u : 0xBF80u) |
              (((r1.x ^ r1.y) & 1u) ? 0x3F800000u : 0xBF800000u);
    }
    uint4 v; v.x = pr[0]; v.y = pr[1]; v.z = pr[2]; v.w = pr[3];
    dst[g] = v;
  }
}

__global__ void k_init(const float* __restrict__ x, float* __restrict__ z, u16* __restrict__ zin,
                       float* __restrict__ lp, float* __restrict__ d0, float* __restrict__ d1) {
  int i = blockIdx.x * 256 + threadIdx.x;
  if (i < BD) { float v = x[i]; z[i] = v; zin[i] = f2bf(v); }
  if (i < B_N) { lp[i] = 0.f; d0[i] = 0.f; d1[i] = 0.f; }
}

__global__ void k_cvtT(const float* __restrict__ src, u16* __restrict__ dst, int R, int C) {
  int i = blockIdx.x * 256 + threadIdx.x;
  if (i >= R * C) return;
  int c = i / R, r = i - c * R;
  dst[i] = f2bf(src[(size_t)r * C + c]);
}
__global__ void k_cvt(const float* __restrict__ src, u16* __restrict__ dst, int n) {
  int i = blockIdx.x * 256 + threadIdx.x;
  if (i < n) dst[i] = f2bf(src[i]);
}

__global__ void k_sentinel(float* __restrict__ out, int n) {
  int i = blockIdx.x * 256 + threadIdx.x;
  if (i < n) out[i] = 12345.0f;
}

// LDS chunk swizzle (R13-verified): chunk c of row r at LDS chunk c^((r>>1)&3).

// Fused 5-product GEMM, 64x64 tiles, K=512. XCD-affine: slab = (bid&7)*4+((bid>>3)>>4).
__global__ __launch_bounds__(256)
void k_f1(const u16* __restrict__ zin, const u16* __restrict__ e0g, const u16* __restrict__ e1g,
          const u16* __restrict__ W1T, const u16* __restrict__ W2b,
          const float* __restrict__ b1v, const float* __restrict__ tw1v, float tstage,
          u16* __restrict__ hbuf, float* __restrict__ div0, float* __restrict__ div1) {
  __shared__ u16 S[2][5 * 2048];
  const int tid = threadIdx.x, wave = tid >> 6, lane = tid & 63;
  const int xcd = blockIdx.x & 7, idx = blockIdx.x >> 3;
  const int bm = xcd * 4 + (idx >> 4);       // slab pinned to XCD
  const int bh = idx & 15;
  const int row0 = bm * 64, col0 = bh * 64;
  const int wm = wave >> 1, wn = wave & 1, r16 = lane & 15, q = lane >> 4;
  const int srow = lane >> 2;
  const int scol = (((lane & 3) ^ ((srow >> 1) & 3))) * 8;   // swizzled source chunk
  const int cqa = (q ^ ((r16 >> 1) & 3)) * 8;                // swizzled read chunk

  f32x4 az[2][2], au0[2][2], au1[2][2], av0[2][2], av1[2][2];
#pragma unroll
  for (int i = 0; i < 2; ++i)
#pragma unroll
    for (int j = 0; j < 2; ++j) {
      az[i][j] = (f32x4){0,0,0,0}; au0[i][j] = (f32x4){0,0,0,0}; au1[i][j] = (f32x4){0,0,0,0};
      av0[i][j] = (f32x4){0,0,0,0}; av1[i][j] = (f32x4){0,0,0,0};
    }

  const size_t arow = (size_t)(row0 + wave * 16 + srow) * 512 + scol;
  const size_t brow = (size_t)(col0 + wave * 16 + srow) * 512 + scol;
  auto stage = [&](int kt, int buf) {
    u16* b = &S[buf][0];
    __builtin_amdgcn_global_load_lds((ga_u32*)(zin + arow + kt), (ls_u32*)(b + 0    + wave * 512), 16, 0, 0);
    __builtin_amdgcn_global_load_lds((ga_u32*)(e0g + arow + kt), (ls_u32*)(b + 2048 + wave * 512), 16, 0, 0);
    __builtin_amdgcn_global_load_lds((ga_u32*)(e1g + arow + kt), (ls_u32*)(b + 4096 + wave * 512), 16, 0, 0);
    __builtin_amdgcn_global_load_lds((ga_u32*)(W1T + brow + kt), (ls_u32*)(b + 6144 + wave * 512), 16, 0, 0);
    __builtin_amdgcn_global_load_lds((ga_u32*)(W2b + brow + kt), (ls_u32*)(b + 8192 + wave * 512), 16, 0, 0);
  };
  stage(0, 0);
  for (int it = 0; it < 16; ++it) {
    const int buf = it & 1;
    __syncthreads();
    if (it + 1 < 16) stage((it + 1) * 32, buf ^ 1);
    const u16* b = &S[buf][0];
    s16x8 zf[2], e0f[2], e1f[2], w1f[2], w2f[2];
#pragma unroll
    for (int i = 0; i < 2; ++i) {
      const int ao = (wm * 32 + i * 16 + r16) * 32 + cqa;
      zf[i]  = *(const s16x8*)(b + 0    + ao);
      e0f[i] = *(const s16x8*)(b + 2048 + ao);
      e1f[i] = *(const s16x8*)(b + 4096 + ao);
    }
#pragma unroll
    for (int j = 0; j < 2; ++j) {
      const int bo = (wn * 32 + j * 16 + r16) * 32 + cqa;
      w1f[j] = *(const s16x8*)(b + 6144 + bo);
      w2f[j] = *(const s16x8*)(b + 8192 + bo);
    }
#pragma unroll
    for (int i = 0; i < 2; ++i)
#pragma unroll
      for (int j = 0; j < 2; ++j) {
        az[i][j]  = __builtin_amdgcn_mfma_f32_16x16x32_bf16(zf[i],  w1f[j], az[i][j],  0, 0, 0);
        au0[i][j] = __builtin_amdgcn_mfma_f32_16x16x32_bf16(e0f[i], w1f[j], au0[i][j], 0, 0, 0);
        au1[i][j] = __builtin_amdgcn_mfma_f32_16x16x32_bf16(e1f[i], w1f[j], au1[i][j], 0, 0, 0);
        av0[i][j] = __builtin_amdgcn_mfma_f32_16x16x32_bf16(e0f[i], w2f[j], av0[i][j], 0, 0, 0);
        av1[i][j] = __builtin_amdgcn_mfma_f32_16x16x32_bf16(e1f[i], w2f[j], av1[i][j], 0, 0, 0);
      }
  }

  float d0s[2][4], d1s[2][4];
#pragma unroll
  for (int i = 0; i < 2; ++i)
#pragma unroll
    for (int r = 0; r < 4; ++r) { d0s[i][r] = 0.f; d1s[i][r] = 0.f; }

#pragma unroll
  for (int j = 0; j < 2; ++j) {
    const int gcol = col0 + wn * 32 + j * 16 + r16;
    const float colb = b1v[gcol] + tstage * tw1v[gcol];
#pragma unroll
    for (int i = 0; i < 2; ++i) {
      const int rbase = row0 + wm * 32 + i * 16 + q * 4;   // C/D: row=quad*4+reg
#pragma unroll
      for (int r = 0; r < 4; ++r) {
        float hv = fast_tanh(az[i][j][r] + colb);
        hbuf[(size_t)(rbase + r) * H_N + gcol] = f2bf(hv);
        float s = 1.f - hv * hv;
        d0s[i][r] += s * au0[i][j][r] * av0[i][j][r];
        d1s[i][r] += s * au1[i][j][r] * av1[i][j][r];
      }
    }
  }
#pragma unroll
  for (int i = 0; i < 2; ++i)
#pragma unroll
    for (int r = 0; r < 4; ++r) {
      float a = d0s[i][r], bb = d1s[i][r];
#pragma unroll
      for (int m = 1; m < 16; m <<= 1) { a += __shfl_xor(a, m); bb += __shfl_xor(bb, m); }
      if (r16 == 0) {
        int grow = row0 + wm * 32 + i * 16 + q * 4 + r;
        atomicAdd(&div0[grow], a);
        atomicAdd(&div1[grow], bb);
      }
    }
}

// GEMM3 (f = h@W2 + b2), 64x32 tiles, K=1024; RK38 epilogue + fused divapply
// + egen for stage sg+4 (R24: folds 8 egen dispatches into f3's tail).
template<int ST>
__global__ __launch_bounds__(256)
void k_f3(const u16* __restrict__ hbuf, const u16* __restrict__ W2T, const float* __restrict__ b2v,
          float* __restrict__ z, float* __restrict__ ACC, float* __restrict__ T,
          u16* __restrict__ zin, float dt,
          float* __restrict__ lp, float* __restrict__ div0, float* __restrict__ div1, float wdt,
          const uint32_t* __restrict__ keys, u16* __restrict__ ebf, int sg) {
  __shared__ u16 S[2][3 * 2048];
  const int tid = threadIdx.x, wave = tid >> 6, lane = tid & 63;
  const int xcd = blockIdx.x & 7, idx = blockIdx.x >> 3;
  const int bm = xcd * 4 + (idx >> 4);       // slab pinned to XCD (matches f1)
  const int bn = idx & 15;
  const int row0 = bm * 64, col0 = bn * 32;
  const int r16 = lane & 15, q = lane >> 4;
  const int srow = lane >> 2;
  const int scol = (((lane & 3) ^ ((srow >> 1) & 3))) * 8;
  const int cqa = (q ^ ((r16 >> 1) & 3)) * 8;

  if (bn == 0 && tid < 64) {
    int b = row0 + tid;
    float c = 0.5f * (div0[b] + div1[b]);
    c = fminf(fmaxf(c, -100.f), 100.f);
    lp[b] -= wdt * c;
    div0[b] = 0.f; div1[b] = 0.f;
  }

  f32x4 acc[2];
  acc[0] = (f32x4){0,0,0,0}; acc[1] = (f32x4){0,0,0,0};

  const size_t arow = (size_t)(row0 + wave * 16 + srow) * 1024 + scol;
  const size_t brow = (size_t)(col0 + (wave & 1) * 16 + srow) * 1024 + scol;
  auto stage = [&](int kt, int buf) {
    u16* b = &S[buf][0];
    __builtin_amdgcn_global_load_lds((ga_u32*)(hbuf + arow + kt), (ls_u32*)(b + wave * 512), 16, 0, 0);
    if (wave < 2)
      __builtin_amdgcn_global_load_lds((ga_u32*)(W2T + brow + kt), (ls_u32*)(b + 4096 + wave * 512), 16, 0, 0);
  };
  stage(0, 0);
  for (int it = 0; it < 32; ++it) {
    const int buf = it & 1;
    __syncthreads();
    if (it + 1 < 32) stage((it + 1) * 32, buf ^ 1);
    const u16* b = &S[buf][0];
    s16x8 af  = *(const s16x8*)(b + (wave * 16 + r16) * 32 + cqa);
    s16x8 bf0 = *(const s16x8*)(b + 4096 + r16 * 32 + cqa);
    s16x8 bf1 = *(const s16x8*)(b + 4096 + (16 + r16) * 32 + cqa);
    acc[0] = __builtin_amdgcn_mfma_f32_16x16x32_bf16(af, bf0, acc[0], 0, 0, 0);
    acc[1] = __builtin_amdgcn_mfma_f32_16x16x32_bf16(af, bf1, acc[1], 0, 0, 0);
  }

#pragma unroll
  for (int j = 0; j < 2; ++j) {
    const int gcol = col0 + j * 16 + r16;
    const float cb = b2v[gcol];
    const int rbase = row0 + wave * 16 + q * 4;
#pragma unroll
    for (int r = 0; r < 4; ++r) {
      const size_t idx2 = (size_t)(rbase + r) * D_N + gcol;
      const float f = acc[j][r] + cb;
      if (ST == 0) {
        ACC[idx2] = dt * 0.125f * f;
        T[idx2]   = dt * f;
        zin[idx2] = f2bf(z[idx2] + dt * f * (1.f / 3.f));
      } else if (ST == 1) {
        float t_ = T[idx2];
        ACC[idx2] += 0.375f * dt * f;
        zin[idx2] = f2bf(z[idx2] + dt * f - t_ * (1.f / 3.f));
        T[idx2]   = t_ - dt * f;
      } else if (ST == 2) {
        ACC[idx2] += 0.375f * dt * f;
        zin[idx2] = f2bf(z[idx2] + T[idx2] + dt * f);
      } else {
        float zn = z[idx2] + ACC[idx2] + dt * 0.125f * f;
        z[idx2]   = zn;
        zin[idx2] = f2bf(zn);
      }
    }
  }

  // egen for stage sg+4 into the e-slot (sg+4)&3 == sg&3, whose last reader
  // f1(sg) retired before this dispatch launched (stream order). 16 elems per
  // thread: per-slab 16 blocks x 256 threads = 4096 tasks = 2 probes x 2048.
  if (sg + 4 < 36) {
    const int stg = sg + 4;
    const int t = bn * 256 + tid;
    const int probe = t >> 11, e16 = t & 2047;
    const uint32_t p0 = (uint32_t)(bm * 32768 + e16 * 16);
    uint32_t k0 = keys[stg * 4 + probe * 2], k1 = keys[stg * 4 + probe * 2 + 1];
    uint4* dst = (uint4*)(ebf + (size_t)(stg & 3) * (2 * (size_t)BD) + (size_t)probe * BD + (size_t)p0);
#pragma unroll
    for (int g = 0; g < 2; ++g) {
      uint32_t pr[4];
#pragma unroll
      for (int h = 0; h < 4; ++h) {
        uint32_t c0 = p0 + g * 8 + h * 2;
        U2 r0 = tf2x32(k0, k1, 0u, c0);
        U2 r1 = tf2x32(k0, k1, 0u, c0 + 1u);
        pr[h] = (((r0.x ^ r0.y) & 1u) ? 0x3F80u : 0xBF80u) |
                (((r1.x ^ r1.y) & 1u) ? 0x3F800000u : 0xBF800000u);
      }
      uint4 v; v.x = pr[0]; v.y = pr[1]; v.z = pr[2]; v.w = pr[3];
      dst[g] = v;
    }
  }
}

// out = [rep (f32, BxD) ; logprob (f32, B)] — XCD-affine row mapping.
__global__ void k_out(const float* __restrict__ z, const float* __restrict__ lp,
                      float* __restrict__ out) {
  const int xcd = blockIdx.x & 7, idx = blockIdx.x >> 3;    // 2048 blocks
  const int b = (xcd * 4 + (idx >> 6)) * 64 + (idx & 63);
  int t = threadIdx.x;
  const float* zr = z + (size_t)b * D_N;
  float ss = 0.f;
  for (int d = t; d < D_N; d += 256) {
    float v = zr[d];
    out[(size_t)b * D_N + d] = v;
    ss += v * v;
  }
  for (int off = 32; off > 0; off >>= 1) ss += __shfl_down(ss, off);
  __shared__ float red[4];
  if ((t & 63) == 0) red[t >> 6] = ss;
  __syncthreads();
  if (t == 0) out[(size_t)BD + b] = -0.5f * (red[0] + red[1] + red[2] + red[3]) + lp[b];
}

extern "C" void kernel_launch(void* const* d_in, const int* in_sizes, int n_in,
                              void* d_out, int out_size, void* d_ws, size_t ws_size,
                              hipStream_t stream) {
  const float* x   = (const float*)d_in[0];
  const float* W1  = (const float*)d_in[1];
  const float* b1  = (const float*)d_in[2];
  const float* tw1 = (const float*)d_in[3];
  const float* W2  = (const float*)d_in[4];
  const float* b2  = (const float*)d_in[5];
  float* outp = (float*)d_out;

  const size_t NEEDED = (size_t)45 << 20;
  if (ws_size < NEEDED) {
    k_sentinel<<<(BD + B_N + 255) / 256, 256, 0, stream>>>(outp, BD + B_N);
    return;
  }
  char* w = (char*)d_ws;
  auto carve = [&](size_t bytes) { char* p = w; w += (bytes + 255) & ~(size_t)255; return p; };
  uint32_t* keys = (uint32_t*)carve(144 * sizeof(uint32_t));
  u16* ebf   = (u16*)carve((size_t)4 * 2 * BD * 2);               // 16 MB: 4-slot e ring
  float* z   = (float*)carve((size_t)BD * 4);
  float* ACC = (float*)carve((size_t)BD * 4);
  float* T   = (float*)carve((size_t)BD * 4);
  u16* zin   = (u16*)carve((size_t)BD * 2);
  u16* hbuf  = (u16*)carve((size_t)B_N * H_N * 2);
  u16* W1T   = (u16*)carve((size_t)H_N * D_N * 2);
  u16* W2b   = (u16*)carve((size_t)H_N * D_N * 2);
  u16* W2T   = (u16*)carve((size_t)D_N * H_N * 2);
  float* lp   = (float*)carve((size_t)B_N * 4);
  float* div0 = (float*)carve((size_t)B_N * 4);
  float* div1 = (float*)carve((size_t)B_N * 4);

  k_keysched<<<1, 1, 0, stream>>>(keys);
  k_init<<<BD / 256, 256, 0, stream>>>(x, z, zin, lp, div0, div1);
  k_cvtT<<<(D_N * H_N) / 256, 256, 0, stream>>>(W1, W1T, D_N, H_N);
  k_cvt <<<(H_N * D_N) / 256, 256, 0, stream>>>(W2, W2b, H_N * D_N);
  k_cvtT<<<(H_N * D_N) / 256, 256, 0, stream>>>(W2, W2T, H_N, D_N);
  k_egen<<<1024, 256, 0, stream>>>(ebf, keys, 0);   // stages 0..3; rest folded into f3

  const int gF1 = (B_N / 64) * (H_N / 64);   // 512
  const int gF3 = (B_N / 64) * (D_N / 32);   // 512

  for (int s = 0; s < 9; ++s) {
    float t0 = (float)s / 9.0f;
    float t1 = (float)(s + 1) / 9.0f;
    float dt = t1 - t0;
    float tst[4] = { t0, t0 + dt / 3.0f, t0 + dt * 2.0f / 3.0f, t1 };
    float wts[4] = { 1.f, 3.f, 3.f, 1.f };
    for (int st = 0; st < 4; ++st) {
      const int sg = s * 4 + st;
      const u16* e0g = ebf + (size_t)(sg & 3) * (2 * (size_t)BD);
      const u16* e1g = e0g + BD;
      k_f1<<<gF1, 256, 0, stream>>>(zin, e0g, e1g, W1T, W2b, b1, tw1, tst[st], hbuf, div0, div1);
      const float wdt = dt * 0.125f * wts[st];
      if (st == 0)      k_f3<0><<<gF3, 256, 0, stream>>>(hbuf, W2T, b2, z, ACC, T, zin, dt, lp, div0, div1, wdt, keys, ebf, sg);
      else if (st == 1) k_f3<1><<<gF3, 256, 0, stream>>>(hbuf, W2T, b2, z, ACC, T, zin, dt, lp, div0, div1, wdt, keys, ebf, sg);
      else if (st == 2) k_f3<2><<<gF3, 256, 0, stream>>>(hbuf, W2T, b2, z, ACC, T, zin, dt, lp, div0, div1, wdt, keys, ebf, sg);
      else              k_f3<3><<<gF3, 256, 0, stream>>>(hbuf, W2T, b2, z, ACC, T, zin, dt, lp, div0, div1, wdt, keys, ebf, sg);
    }
  }
  k_out<<<B_N, 256, 0, stream>>>(z, lp, outp);
}